// Round 2
// baseline (1099.523 us; speedup 1.0000x reference)
//
#include <hip/hip_runtime.h>

typedef unsigned short u16;
typedef unsigned int u32;
typedef long long i64;
typedef __attribute__((ext_vector_type(4))) float f32x4;
typedef __attribute__((ext_vector_type(8))) __bf16 bf16x8;

#define DEVI static __device__ __forceinline__

constexpr int kB = 4, kS = 2048, kD = 512, kH = 8;
constexpr int kND = kD * kH;     // 4096
constexpr int kBS = kB * kS;     // 8192
constexpr int kNQKV = 3 * kND;   // 12288
constexpr float kScale = 0.044194173824159216f;  // 512^-0.5

DEVI u16 f2bf(float f) {
  u32 u = __builtin_bit_cast(u32, f);
  return (u16)((u + 0x7fffu + ((u >> 16) & 1u)) >> 16);
}
DEVI float bf2f(u16 h) { return __builtin_bit_cast(float, (u32)h << 16); }

DEVI f32x4 mfma16(bf16x8 a, bf16x8 b, f32x4 c) {
  return __builtin_amdgcn_mfma_f32_16x16x32_bf16(a, b, c, 0, 0, 0);
}

// global -> LDS direct DMA, 16B per lane (wave-uniform LDS base + lane*16)
DEVI void gld16(const u16* g, u16* l) {
  __builtin_amdgcn_global_load_lds(
      (const __attribute__((address_space(1))) void*)g,
      (__attribute__((address_space(3))) void*)l, 16, 0, 0);
}

__global__ void k_zero(float* __restrict__ p, int n) {
  int i = blockIdx.x * 256 + threadIdx.x;
  if (i < n) p[i] = 0.0f;
}

// concat q_b|k_b|v_b -> [12288]
__global__ void k_cat3(const float* __restrict__ a, const float* __restrict__ b,
                       const float* __restrict__ c, float* __restrict__ o) {
  int i = blockIdx.x * 256 + threadIdx.x;
  if (i < kND) o[i] = a[i];
  else if (i < 2 * kND) o[i] = b[i - kND];
  else if (i < 3 * kND) o[i] = c[i - 2 * kND];
}

// ---------------- LayerNorm: fp32 [8192,512] -> bf16 xn ----------------
__global__ __launch_bounds__(256) void k_ln(const float* __restrict__ x,
                                            const float* __restrict__ lw,
                                            const float* __restrict__ lb,
                                            u16* __restrict__ xn) {
  const int lane = threadIdx.x & 63;
  const int row = (blockIdx.x << 2) + (threadIdx.x >> 6);
  const float4* xp = reinterpret_cast<const float4*>(x + (size_t)row * kD);
  float4 a = xp[lane * 2], b = xp[lane * 2 + 1];
  float s = a.x + a.y + a.z + a.w + b.x + b.y + b.z + b.w;
  float ss = a.x * a.x + a.y * a.y + a.z * a.z + a.w * a.w +
             b.x * b.x + b.y * b.y + b.z * b.z + b.w * b.w;
#pragma unroll
  for (int m = 1; m < 64; m <<= 1) {
    s += __shfl_xor(s, m, 64);
    ss += __shfl_xor(ss, m, 64);
  }
  const float mean = s * (1.0f / kD);
  const float var = ss * (1.0f / kD) - mean * mean;
  const float rstd = rsqrtf(fmaxf(var, 0.0f) + 1e-5f);
  const float4* wp = reinterpret_cast<const float4*>(lw);
  const float4* bp = reinterpret_cast<const float4*>(lb);
  float4 w0 = wp[lane * 2], w1 = wp[lane * 2 + 1];
  float4 b0 = bp[lane * 2], b1 = bp[lane * 2 + 1];
  float o0 = (a.x - mean) * rstd * w0.x + b0.x;
  float o1 = (a.y - mean) * rstd * w0.y + b0.y;
  float o2 = (a.z - mean) * rstd * w0.z + b0.z;
  float o3 = (a.w - mean) * rstd * w0.w + b0.w;
  float o4 = (b.x - mean) * rstd * w1.x + b1.x;
  float o5 = (b.y - mean) * rstd * w1.y + b1.y;
  float o6 = (b.z - mean) * rstd * w1.z + b1.z;
  float o7 = (b.w - mean) * rstd * w1.w + b1.w;
  uint4 st = make_uint4((u32)f2bf(o0) | ((u32)f2bf(o1) << 16),
                        (u32)f2bf(o2) | ((u32)f2bf(o3) << 16),
                        (u32)f2bf(o4) | ((u32)f2bf(o5) << 16),
                        (u32)f2bf(o6) | ((u32)f2bf(o7) << 16));
  *reinterpret_cast<uint4*>(xn + (size_t)row * kD + lane * 8) = st;
}

// ------------- weight transpose: fp32 [R,C] -> bf16 [C,R] -------------
__global__ void k_wt(const float* __restrict__ in, u16* __restrict__ out,
                     int R, int C) {
  __shared__ float t[32][33];
  const int tx = threadIdx.x, ty = threadIdx.y;
  const int c0 = blockIdx.x << 5, r0 = blockIdx.y << 5;
#pragma unroll
  for (int i = 0; i < 4; i++)
    t[ty + 8 * i][tx] = in[(size_t)(r0 + ty + 8 * i) * C + c0 + tx];
  __syncthreads();
#pragma unroll
  for (int i = 0; i < 4; i++)
    out[(size_t)(c0 + ty + 8 * i) * R + r0 + tx] = f2bf(t[tx][ty + 8 * i]);
}

// ------- V transpose: bf16 V[2048, d-slice] -> VT[z][512][2048] -------
// z offset into V decomposed: z*sVz + (z>>3)*sVzH  (z = b*8+h)
__global__ void k_vt(const u16* __restrict__ V, u16* __restrict__ VT, int ldv,
                     i64 sVz, i64 sVzH, i64 sTz) {
  const int z = blockIdx.z;
  V += (size_t)((i64)z * sVz + (i64)(z >> 3) * sVzH);
  VT += (size_t)((i64)z * sTz);
  __shared__ u16 t[32][33];
  const int tx = threadIdx.x, ty = threadIdx.y;
  const int s0 = blockIdx.x << 5, d0 = blockIdx.y << 5;
#pragma unroll
  for (int i = 0; i < 4; i++)
    t[ty + 8 * i][tx] = V[(size_t)(s0 + ty + 8 * i) * ldv + d0 + tx];
  __syncthreads();
#pragma unroll
  for (int i = 0; i < 4; i++)
    VT[(size_t)(d0 + ty + 8 * i) * kS + s0 + tx] = t[tx][ty + 8 * i];
}

// ---------------- GEMM: C[M,N] = A[M,K] * Bt[N,K]^T (+epilogue) -------
// m97-style: global_load_lds(16B) staging, double-buffered LDS,
// ONE barrier per K-step (stage k+1 into buf^1 while MFMA-ing buf).
// z offsets decomposed as z*s + (z>>3)*sH so one launch can span all
// (b,h) pairs even when batch stride != 8*head stride.
// EPI 0: bf16 out + bias                                    (QKV proj)
// EPI 1: f32  out + bias                                    (O-proj first)
// EPI 4: f32  out += acc                                    (O-proj accum)
// EPI 2: bf16 out = exp(acc*scale), atomic row-sums -> lrow (QK^T)
// EPI 3: bf16 out = acc / lrow[row]                          (P@V)
template <int EPI>
__global__ __launch_bounds__(256) void k_gemm(
    const u16* __restrict__ A, int lda, i64 sAz, i64 sAzH,
    const u16* __restrict__ Bt, int ldb, i64 sBz, i64 sBzH,
    void* __restrict__ Cb, int ldc, i64 sCz, i64 sCzH, int K,
    const float* __restrict__ bias, float* __restrict__ lbase, i64 sLz) {
  const int z = blockIdx.z;
  A += (size_t)((i64)z * sAz + (i64)(z >> 3) * sAzH);
  Bt += (size_t)((i64)z * sBz + (i64)(z >> 3) * sBzH);
  const i64 czoff = (i64)z * sCz + (i64)(z >> 3) * sCzH;
  float* lrow = lbase + (size_t)z * sLz;

  // linear LDS tiles (gload_lds needs contiguous lane-order dest): [128][32]
  __shared__ u16 As[2][128 * 32];
  __shared__ u16 Bs[2][128 * 32];

  const int tid = threadIdx.x;
  const int lane = tid & 63, wid = tid >> 6;
  const int g = lane >> 4, lr = lane & 15;
  const int wr = wid >> 1, wc = wid & 1;
  const int m0 = blockIdx.x << 7, n0 = blockIdx.y << 7;

  // staging geometry: wave w covers rows [32w,32w+32) of the tile in two
  // 1KB chunks; lane l -> row 32w+(l>>2) (+16 for chunk 1), col (l&3)*8
  const int srow = (wid << 5) + (lane >> 2);
  const int scol = (lane & 3) << 3;
  const u16* agp0 = A + (size_t)(m0 + srow) * lda + scol;
  const u16* agp1 = A + (size_t)(m0 + srow + 16) * lda + scol;
  const u16* bgp0 = Bt + (size_t)(n0 + srow) * ldb + scol;
  const u16* bgp1 = Bt + (size_t)(n0 + srow + 16) * ldb + scol;

  f32x4 acc[4][4] = {};

  auto stage = [&](int ks, int buf) {
    const int ko = ks << 5;
    u16* ab = &As[buf][wid << 10];  // wave-uniform chunk base
    u16* bb = &Bs[buf][wid << 10];
    gld16(agp0 + ko, ab);
    gld16(agp1 + ko, ab + 512);
    gld16(bgp0 + ko, bb);
    gld16(bgp1 + ko, bb + 512);
  };

  const int nsteps = K >> 5;
  stage(0, 0);
  for (int ks = 0; ks < nsteps; ++ks) {
    const int cur = ks & 1;
    __syncthreads();  // drains vmcnt -> tile `cur` ready; prior reads done
    if (ks + 1 < nsteps) stage(ks + 1, cur ^ 1);
    bf16x8 af[4], bfr[4];
#pragma unroll
    for (int m = 0; m < 4; m++)
      af[m] = *reinterpret_cast<const bf16x8*>(
          &As[cur][(wr * 64 + m * 16 + lr) * 32 + g * 8]);
#pragma unroll
    for (int n = 0; n < 4; n++)
      bfr[n] = *reinterpret_cast<const bf16x8*>(
          &Bs[cur][(wc * 64 + n * 16 + lr) * 32 + g * 8]);
#pragma unroll
    for (int m = 0; m < 4; m++)
#pragma unroll
      for (int n = 0; n < 4; n++) acc[m][n] = mfma16(af[m], bfr[n], acc[m][n]);
  }

  const int crow0 = m0 + wr * 64;
  const int ccol0 = n0 + wc * 64;

  if constexpr (EPI == 0) {
    u16* C16 = (u16*)Cb + (size_t)czoff;
#pragma unroll
    for (int n = 0; n < 4; n++) {
      const int col = ccol0 + n * 16 + lr;
      const float bv = bias[col];
#pragma unroll
      for (int m = 0; m < 4; m++)
#pragma unroll
        for (int j = 0; j < 4; j++) {
          const int row = crow0 + m * 16 + (g << 2) + j;
          C16[(size_t)row * ldc + col] = f2bf(acc[m][n][j] + bv);
        }
    }
  } else if constexpr (EPI == 1 || EPI == 4) {
    float* C32 = (float*)Cb + (size_t)czoff;
#pragma unroll
    for (int n = 0; n < 4; n++) {
      const int col = ccol0 + n * 16 + lr;
      const float bv = (EPI == 1) ? bias[col] : 0.0f;
#pragma unroll
      for (int m = 0; m < 4; m++)
#pragma unroll
        for (int j = 0; j < 4; j++) {
          const int row = crow0 + m * 16 + (g << 2) + j;
          float v = acc[m][n][j] + bv;
          if constexpr (EPI == 4) v += C32[(size_t)row * ldc + col];
          C32[(size_t)row * ldc + col] = v;
        }
    }
  } else if constexpr (EPI == 2) {
    u16* C16 = (u16*)Cb + (size_t)czoff;
#pragma unroll
    for (int m = 0; m < 4; m++) {
      float rsum[4] = {0.f, 0.f, 0.f, 0.f};
#pragma unroll
      for (int n = 0; n < 4; n++) {
        const int col = ccol0 + n * 16 + lr;
#pragma unroll
        for (int j = 0; j < 4; j++) {
          const float p = __expf(acc[m][n][j] * kScale);
          const u16 pb = f2bf(p);
          C16[(size_t)(crow0 + m * 16 + (g << 2) + j) * ldc + col] = pb;
          rsum[j] += bf2f(pb);  // keep l consistent with stored bf16 P
        }
      }
#pragma unroll
      for (int j = 0; j < 4; j++) {
        float r = rsum[j];
        r += __shfl_xor(r, 1, 64);
        r += __shfl_xor(r, 2, 64);
        r += __shfl_xor(r, 4, 64);
        r += __shfl_xor(r, 8, 64);
        if (lr == 0) atomicAdd(&lrow[crow0 + m * 16 + (g << 2) + j], r);
      }
    }
  } else {  // EPI == 3
    u16* C16 = (u16*)Cb + (size_t)czoff;
#pragma unroll
    for (int m = 0; m < 4; m++)
#pragma unroll
      for (int j = 0; j < 4; j++) {
        const int row = crow0 + m * 16 + (g << 2) + j;
        const float inv = 1.0f / lrow[row];
#pragma unroll
        for (int n = 0; n < 4; n++) {
          const int col = ccol0 + n * 16 + lr;
          C16[(size_t)row * ldc + col] = f2bf(acc[m][n][j] * inv);
        }
      }
  }
}

extern "C" void kernel_launch(void* const* d_in, const int* in_sizes, int n_in,
                              void* d_out, int out_size, void* d_ws,
                              size_t ws_size, hipStream_t stream) {
  const float* x = (const float*)d_in[0];
  const float* ln_w = (const float*)d_in[1];
  const float* ln_b = (const float*)d_in[2];
  const float* q_w = (const float*)d_in[3];
  const float* q_b = (const float*)d_in[4];
  const float* k_w = (const float*)d_in[5];
  const float* k_b = (const float*)d_in[6];
  const float* v_w = (const float*)d_in[7];
  const float* v_b = (const float*)d_in[8];
  const float* o_w = (const float*)d_in[9];
  const float* o_b = (const float*)d_in[10];
  float* out = (float*)d_out;

  // ---- workspace plan, adaptive to ws_size ----
  constexpr size_t SZ_XN = (size_t)kBS * kD * 2;        // 8 MB
  constexpr size_t SZ_QKVT = (size_t)kNQKV * kD * 2;    // 12 MB
  constexpr size_t SZ_OWT = (size_t)kND * kD * 2;       // 4 MB
  constexpr size_t SZ_CB = (size_t)kNQKV * 4;           // 48 KB
  constexpr size_t SZ_LB = (size_t)32 * kS * 4;         // 256 KB
  constexpr size_t SZ_QKV = (size_t)kBS * kNQKV * 2;    // 192 MB
  constexpr size_t SZ_VT = (size_t)32 * kD * kS * 2;    // 64 MB
  constexpr size_t SZ_AO = (size_t)kBS * kND * 2;       // 64 MB
  constexpr size_t SZ_S = (size_t)kS * kS * 2;          // 8 MB per z
  constexpr size_t SZ_H = (size_t)kBS * kD * 2;         // 8 MB per head
  constexpr size_t SZ_BH = (size_t)kS * kD * 2;         // 2 MB per (b,h)
  const size_t common = SZ_XN + SZ_QKVT + SZ_OWT + SZ_CB + SZ_LB;

  char* p = (char*)d_ws;
  auto alloc = [&](size_t bytes) {
    char* r = p;
    p += (bytes + 255) & ~(size_t)255;
    return r;
  };
  auto fits = [&](size_t extra) { return common + extra + 4096 <= ws_size; };

  const size_t fusedExtra = SZ_QKV + SZ_VT + SZ_AO;  // 320 MB
  int plan, zc;
  if (fits(fusedExtra + 32 * SZ_S)) { plan = 0; zc = 32; }
  else if (fits(fusedExtra + 16 * SZ_S)) { plan = 0; zc = 16; }
  else if (fits(fusedExtra + 8 * SZ_S)) { plan = 0; zc = 8; }
  else if (fits(fusedExtra + 4 * SZ_S)) { plan = 0; zc = 4; }
  else if (fits(fusedExtra + 2 * SZ_S)) { plan = 0; zc = 2; }
  else if (fits(fusedExtra + 1 * SZ_S)) { plan = 0; zc = 1; }
  else if (fits(4 * SZ_H + SZ_AO + 4 * SZ_S)) { plan = 1; zc = 4; }
  else if (fits(4 * SZ_H + SZ_AO + 1 * SZ_S)) { plan = 1; zc = 1; }
  else if (fits(5 * SZ_H + 4 * SZ_S)) { plan = 2; zc = 4; }
  else if (fits(5 * SZ_H + 1 * SZ_S)) { plan = 2; zc = 1; }
  else { plan = 3; zc = 1; }

  u16* xn = (u16*)alloc(SZ_XN);
  u16* qkvT = (u16*)alloc(SZ_QKVT);  // q rows [0,4096), k [4096,8192), v [8192,12288)
  u16* owT = (u16*)alloc(SZ_OWT);
  float* cbias = (float*)alloc(SZ_CB);
  float* lbuf = (float*)alloc(SZ_LB);

  u16* kwT = qkvT + (size_t)kND * kD;
  u16* vwT = qkvT + (size_t)2 * kND * kD;

  // ---- common pre-work ----
  k_zero<<<dim3(256), 256, 0, stream>>>(lbuf, 32 * kS);
  k_ln<<<dim3(kBS / 4), 256, 0, stream>>>(x, ln_w, ln_b, xn);
  dim3 tb(32, 8);
  k_wt<<<dim3(kND / 32, kD / 32), tb, 0, stream>>>(q_w, qkvT, kD, kND);
  k_wt<<<dim3(kND / 32, kD / 32), tb, 0, stream>>>(k_w, kwT, kD, kND);
  k_wt<<<dim3(kND / 32, kD / 32), tb, 0, stream>>>(v_w, vwT, kD, kND);
  k_wt<<<dim3(kD / 32, kND / 32), tb, 0, stream>>>(o_w, owT, kND, kD);

  const i64 sS = (i64)kS * kS;  // S tile stride (elems)

  if (plan == 0) {
    // ---- fused plan: one QKV GEMM, z-merged attention core ----
    u16* QKV = (u16*)alloc(SZ_QKV);  // [8192, 12288]: Q|K|V per row
    u16* VTb = (u16*)alloc(SZ_VT);   // [32][512][2048]
    u16* AOb = (u16*)alloc(SZ_AO);   // [8192, 4096]
    u16* Sb = (u16*)alloc((size_t)zc * SZ_S);

    k_cat3<<<dim3(kNQKV / 256), 256, 0, stream>>>(q_b, k_b, v_b, cbias);
    // fused QKV projection: [8192,512] x [12288,512]^T -> [8192,12288]
    k_gemm<0><<<dim3(kBS / 128, kNQKV / 128), 256, 0, stream>>>(
        xn, kD, 0, 0, qkvT, kD, 0, 0, QKV, kNQKV, 0, 0, kD, cbias, nullptr, 0);
    // V transpose, all 32 (b,h) in one launch
    const i64 sHiQ = (i64)kS * kNQKV - 8 * kD;  // extra jump at b boundary
    k_vt<<<dim3(kS / 32, kD / 32, 32), tb, 0, stream>>>(
        QKV + (size_t)2 * kND, VTb, kNQKV, kD, sHiQ, (i64)kD * kS);

    const u16* Qb = QKV;
    const u16* Kb = QKV + kND;
    const i64 sHiAO = (i64)kS * kND - 8 * kD;
    for (int z0 = 0; z0 < 32; z0 += zc) {
      const i64 qoff = (i64)z0 * kD + (i64)(z0 >> 3) * sHiQ;
      const i64 aoff = (i64)z0 * kD + (i64)(z0 >> 3) * sHiAO;
      float* lr0 = lbuf + (size_t)z0 * kS;
      k_gemm<2><<<dim3(16, 16, zc), 256, 0, stream>>>(
          Qb + qoff, kNQKV, kD, sHiQ, Kb + qoff, kNQKV, kD, sHiQ, Sb, kS, sS,
          0, kD, nullptr, lr0, kS);
      k_gemm<3><<<dim3(16, 4, zc), 256, 0, stream>>>(
          Sb, kS, sS, 0, VTb + (size_t)z0 * kD * kS, kS, (i64)kD * kS, 0,
          AOb + aoff, kND, kD, sHiAO, kS, nullptr, lr0, kS);
    }
    k_gemm<1><<<dim3(64, 4), 256, 0, stream>>>(AOb, kND, 0, 0, owT, kND, 0, 0,
                                               out, kD, 0, 0, kND, o_b,
                                               nullptr, 0);
  } else if (plan == 1 || plan == 2) {
    u16* Qh = (u16*)alloc(SZ_H);
    u16* Kh = (u16*)alloc(SZ_H);
    u16* Vh = (u16*)alloc(SZ_H);
    u16* VTh = (u16*)alloc(SZ_H);
    u16* AO = (u16*)alloc(plan == 1 ? SZ_AO : SZ_H);
    u16* Sb = (u16*)alloc((size_t)zc * SZ_S);
    const int aold = (plan == 1) ? kND : kD;

    for (int h = 0; h < kH; h++) {
      const u16* qwh = qkvT + (size_t)h * kD * kD;
      const u16* kwh = kwT + (size_t)h * kD * kD;
      const u16* vwh = vwT + (size_t)h * kD * kD;
      k_gemm<0><<<dim3(64, 4), 256, 0, stream>>>(xn, kD, 0, 0, qwh, kD, 0, 0,
                                                 Qh, kD, 0, 0, kD, q_b + h * kD,
                                                 nullptr, 0);
      k_gemm<0><<<dim3(64, 4), 256, 0, stream>>>(xn, kD, 0, 0, kwh, kD, 0, 0,
                                                 Kh, kD, 0, 0, kD, k_b + h * kD,
                                                 nullptr, 0);
      k_gemm<0><<<dim3(64, 4), 256, 0, stream>>>(xn, kD, 0, 0, vwh, kD, 0, 0,
                                                 Vh, kD, 0, 0, kD, v_b + h * kD,
                                                 nullptr, 0);
      k_vt<<<dim3(64, 16, 4), tb, 0, stream>>>(Vh, VTh, kD, (i64)kS * kD, 0,
                                               (i64)kD * kS);
      u16* AOh = (plan == 1) ? AO + (size_t)h * kD : AO;
      const i64 sAO = (plan == 1) ? (i64)kS * kND : (i64)kS * kD;
      for (int b0 = 0; b0 < kB; b0 += zc) {
        float* lr0 = lbuf + (size_t)(h * 4 + b0) * kS;
        k_gemm<2><<<dim3(16, 16, zc), 256, 0, stream>>>(
            Qh + (size_t)b0 * kS * kD, kD, (i64)kS * kD, 0,
            Kh + (size_t)b0 * kS * kD, kD, (i64)kS * kD, 0, Sb, kS, sS, 0, kD,
            nullptr, lr0, kS);
        k_gemm<3><<<dim3(16, 4, zc), 256, 0, stream>>>(
            Sb, kS, sS, 0, VTh + (size_t)b0 * kD * kS, kS, (i64)kD * kS, 0,
            AOh + (size_t)b0 * kS * aold, aold, sAO, 0, kS, nullptr, lr0, kS);
      }
      if (plan == 2) {
        if (h == 0)
          k_gemm<1><<<dim3(64, 4), 256, 0, stream>>>(
              AO, kD, 0, 0, owT + (size_t)h * kD, kND, 0, 0, out, kD, 0, 0, kD,
              o_b, nullptr, 0);
        else
          k_gemm<4><<<dim3(64, 4), 256, 0, stream>>>(
              AO, kD, 0, 0, owT + (size_t)h * kD, kND, 0, 0, out, kD, 0, 0, kD,
              nullptr, nullptr, 0);
      }
    }
    if (plan == 1)
      k_gemm<1><<<dim3(64, 4), 256, 0, stream>>>(AO, kND, 0, 0, owT, kND, 0, 0,
                                                 out, kD, 0, 0, kND, o_b,
                                                 nullptr, 0);
  } else {
    u16* Qbh = (u16*)alloc(SZ_BH);
    u16* Kbh = (u16*)alloc(SZ_BH);
    u16* Vbh = (u16*)alloc(SZ_BH);
    u16* VTbh = (u16*)alloc(SZ_BH);
    u16* AObh = (u16*)alloc(SZ_BH);
    u16* Sb = (u16*)alloc(SZ_S);

    for (int b = 0; b < kB; b++)
      for (int h = 0; h < kH; h++) {
        const u16* xb = xn + (size_t)b * kS * kD;
        k_gemm<0><<<dim3(16, 4), 256, 0, stream>>>(
            xb, kD, 0, 0, qkvT + (size_t)h * kD * kD, kD, 0, 0, Qbh, kD, 0, 0,
            kD, q_b + h * kD, nullptr, 0);
        k_gemm<0><<<dim3(16, 4), 256, 0, stream>>>(
            xb, kD, 0, 0, kwT + (size_t)h * kD * kD, kD, 0, 0, Kbh, kD, 0, 0,
            kD, k_b + h * kD, nullptr, 0);
        k_gemm<0><<<dim3(16, 4), 256, 0, stream>>>(
            xb, kD, 0, 0, vwT + (size_t)h * kD * kD, kD, 0, 0, Vbh, kD, 0, 0,
            kD, v_b + h * kD, nullptr, 0);
        k_vt<<<dim3(64, 16, 1), tb, 0, stream>>>(Vbh, VTbh, kD, 0, 0, 0);
        float* lr0 = lbuf + (size_t)(b * 8 + h) * kS;
        k_gemm<2><<<dim3(16, 16, 1), 256, 0, stream>>>(
            Qbh, kD, 0, 0, Kbh, kD, 0, 0, Sb, kS, 0, 0, kD, nullptr, lr0, 0);
        k_gemm<3><<<dim3(16, 4, 1), 256, 0, stream>>>(
            Sb, kS, 0, 0, VTbh, kS, 0, 0, AObh, kD, 0, 0, kS, nullptr, lr0, 0);
        float* outb = out + (size_t)b * kS * kD;
        if (h == 0)
          k_gemm<1><<<dim3(16, 4), 256, 0, stream>>>(
              AObh, kD, 0, 0, owT, kND, 0, 0, outb, kD, 0, 0, kD, o_b, nullptr,
              0);
        else
          k_gemm<4><<<dim3(16, 4), 256, 0, stream>>>(
              AObh, kD, 0, 0, owT + (size_t)h * kD, kND, 0, 0, outb, kD, 0, 0,
              kD, nullptr, nullptr, 0);
      }
  }
}

// Round 3
// 1089.094 us; speedup vs baseline: 1.0096x; 1.0096x over previous
//
#include <hip/hip_runtime.h>

typedef unsigned short u16;
typedef unsigned int u32;
typedef long long i64;
typedef __attribute__((ext_vector_type(4))) float f32x4;
typedef __attribute__((ext_vector_type(8))) __bf16 bf16x8;

#define DEVI static __device__ __forceinline__

constexpr int kB = 4, kS = 2048, kD = 512, kH = 8;
constexpr int kND = kD * kH;     // 4096
constexpr int kBS = kB * kS;     // 8192
constexpr int kNQK = 2 * kND;    // 8192
constexpr int kNQKV = 3 * kND;   // 12288
constexpr float kScale = 0.044194173824159216f;  // 512^-0.5

DEVI u16 f2bf(float f) {
  u32 u = __builtin_bit_cast(u32, f);
  return (u16)((u + 0x7fffu + ((u >> 16) & 1u)) >> 16);
}
DEVI float bf2f(u16 h) { return __builtin_bit_cast(float, (u32)h << 16); }

DEVI f32x4 mfma16(bf16x8 a, bf16x8 b, f32x4 c) {
  return __builtin_amdgcn_mfma_f32_16x16x32_bf16(a, b, c, 0, 0, 0);
}

// global -> LDS direct DMA, 16B per lane (wave-uniform LDS base + lane*16)
DEVI void gld16(const u16* g, u16* l) {
  __builtin_amdgcn_global_load_lds(
      (const __attribute__((address_space(1))) void*)g,
      (__attribute__((address_space(3))) void*)l, 16, 0, 0);
}

__global__ void k_zero(float* __restrict__ p, int n) {
  int i = blockIdx.x * 256 + threadIdx.x;
  if (i < n) p[i] = 0.0f;
}

// concat q_b|k_b -> [8192] (cols of the fused QK projection)
__global__ void k_cat2(const float* __restrict__ a, const float* __restrict__ b,
                       float* __restrict__ o) {
  int i = blockIdx.x * 256 + threadIdx.x;
  if (i < kND) o[i] = a[i];
  else if (i < 2 * kND) o[i] = b[i - kND];
}

// ---------------- LayerNorm: fp32 [8192,512] -> bf16 xn ----------------
__global__ __launch_bounds__(256) void k_ln(const float* __restrict__ x,
                                            const float* __restrict__ lw,
                                            const float* __restrict__ lb,
                                            u16* __restrict__ xn) {
  const int lane = threadIdx.x & 63;
  const int row = (blockIdx.x << 2) + (threadIdx.x >> 6);
  const float4* xp = reinterpret_cast<const float4*>(x + (size_t)row * kD);
  float4 a = xp[lane * 2], b = xp[lane * 2 + 1];
  float s = a.x + a.y + a.z + a.w + b.x + b.y + b.z + b.w;
  float ss = a.x * a.x + a.y * a.y + a.z * a.z + a.w * a.w +
             b.x * b.x + b.y * b.y + b.z * b.z + b.w * b.w;
#pragma unroll
  for (int m = 1; m < 64; m <<= 1) {
    s += __shfl_xor(s, m, 64);
    ss += __shfl_xor(ss, m, 64);
  }
  const float mean = s * (1.0f / kD);
  const float var = ss * (1.0f / kD) - mean * mean;
  const float rstd = rsqrtf(fmaxf(var, 0.0f) + 1e-5f);
  const float4* wp = reinterpret_cast<const float4*>(lw);
  const float4* bp = reinterpret_cast<const float4*>(lb);
  float4 w0 = wp[lane * 2], w1 = wp[lane * 2 + 1];
  float4 b0 = bp[lane * 2], b1 = bp[lane * 2 + 1];
  float o0 = (a.x - mean) * rstd * w0.x + b0.x;
  float o1 = (a.y - mean) * rstd * w0.y + b0.y;
  float o2 = (a.z - mean) * rstd * w0.z + b0.z;
  float o3 = (a.w - mean) * rstd * w0.w + b0.w;
  float o4 = (b.x - mean) * rstd * w1.x + b1.x;
  float o5 = (b.y - mean) * rstd * w1.y + b1.y;
  float o6 = (b.z - mean) * rstd * w1.z + b1.z;
  float o7 = (b.w - mean) * rstd * w1.w + b1.w;
  uint4 st = make_uint4((u32)f2bf(o0) | ((u32)f2bf(o1) << 16),
                        (u32)f2bf(o2) | ((u32)f2bf(o3) << 16),
                        (u32)f2bf(o4) | ((u32)f2bf(o5) << 16),
                        (u32)f2bf(o6) | ((u32)f2bf(o7) << 16));
  *reinterpret_cast<uint4*>(xn + (size_t)row * kD + lane * 8) = st;
}

// ------------- weight transpose: fp32 [R,C] -> bf16 [C,R] -------------
__global__ void k_wt(const float* __restrict__ in, u16* __restrict__ out,
                     int R, int C) {
  __shared__ float t[32][33];
  const int tx = threadIdx.x, ty = threadIdx.y;
  const int c0 = blockIdx.x << 5, r0 = blockIdx.y << 5;
#pragma unroll
  for (int i = 0; i < 4; i++)
    t[ty + 8 * i][tx] = in[(size_t)(r0 + ty + 8 * i) * C + c0 + tx];
  __syncthreads();
#pragma unroll
  for (int i = 0; i < 4; i++)
    out[(size_t)(c0 + ty + 8 * i) * R + r0 + tx] = f2bf(t[tx][ty + 8 * i]);
}

// ------- V transpose: bf16 V[2048, d-slice] -> VT[z][512][2048] -------
// (used only by fallback plans 1-3)
__global__ void k_vt(const u16* __restrict__ V, u16* __restrict__ VT, int ldv,
                     i64 sVz, i64 sVzH, i64 sTz) {
  const int z = blockIdx.z;
  V += (size_t)((i64)z * sVz + (i64)(z >> 3) * sVzH);
  VT += (size_t)((i64)z * sTz);
  __shared__ u16 t[32][33];
  const int tx = threadIdx.x, ty = threadIdx.y;
  const int s0 = blockIdx.x << 5, d0 = blockIdx.y << 5;
#pragma unroll
  for (int i = 0; i < 4; i++)
    t[ty + 8 * i][tx] = V[(size_t)(s0 + ty + 8 * i) * ldv + d0 + tx];
  __syncthreads();
#pragma unroll
  for (int i = 0; i < 4; i++)
    VT[(size_t)(d0 + ty + 8 * i) * kS + s0 + tx] = t[tx][ty + 8 * i];
}

// ---------------- GEMM: C[M,N] = A[M,K] * Bt[N,K]^T (+epilogue) -------
// m97-style: global_load_lds(16B) staging, double-buffered LDS,
// ONE barrier per K-step (stage k+1 into buf^1 while MFMA-ing buf).
// z offsets decomposed as z*s + (z>>3)*sH so one launch can span all
// (b,h) pairs even when batch stride != 8*head stride.
// EPI 0: bf16 out + bias                                    (QK proj)
// EPI 1: f32  out + bias                                    (O-proj first)
// EPI 4: f32  out += acc                                    (O-proj accum)
// EPI 2: bf16 out = exp(acc*scale), atomic row-sums -> lrow (QK^T)
// EPI 3: bf16 out = acc / lrow[row]                          (P@V)
// EPI 5: V-proj: bf16 (acc+bias) written TRANSPOSED into VT[z][d][s]
template <int EPI>
__global__ __launch_bounds__(256) void k_gemm(
    const u16* __restrict__ A, int lda, i64 sAz, i64 sAzH,
    const u16* __restrict__ Bt, int ldb, i64 sBz, i64 sBzH,
    void* __restrict__ Cb, int ldc, i64 sCz, i64 sCzH, int K,
    const float* __restrict__ bias, float* __restrict__ lbase, i64 sLz) {
  const int z = blockIdx.z;
  A += (size_t)((i64)z * sAz + (i64)(z >> 3) * sAzH);
  Bt += (size_t)((i64)z * sBz + (i64)(z >> 3) * sBzH);
  const i64 czoff = (i64)z * sCz + (i64)(z >> 3) * sCzH;
  float* lrow = lbase + (size_t)z * sLz;

  // linear LDS tiles (gload_lds needs contiguous lane-order dest): [128][32]
  __shared__ u16 As[2][128 * 32];
  __shared__ u16 Bs[2][128 * 32];

  const int tid = threadIdx.x;
  const int lane = tid & 63, wid = tid >> 6;
  const int g = lane >> 4, lr = lane & 15;
  const int wr = wid >> 1, wc = wid & 1;
  const int m0 = blockIdx.x << 7, n0 = blockIdx.y << 7;

  // staging geometry: wave w covers rows [32w,32w+32) of the tile in two
  // 1KB chunks; lane l -> row 32w+(l>>2) (+16 for chunk 1), col (l&3)*8
  const int srow = (wid << 5) + (lane >> 2);
  const int scol = (lane & 3) << 3;
  const u16* agp0 = A + (size_t)(m0 + srow) * lda + scol;
  const u16* agp1 = A + (size_t)(m0 + srow + 16) * lda + scol;
  const u16* bgp0 = Bt + (size_t)(n0 + srow) * ldb + scol;
  const u16* bgp1 = Bt + (size_t)(n0 + srow + 16) * ldb + scol;

  f32x4 acc[4][4] = {};

  auto stage = [&](int ks, int buf) {
    const int ko = ks << 5;
    u16* ab = &As[buf][wid << 10];  // wave-uniform chunk base
    u16* bb = &Bs[buf][wid << 10];
    gld16(agp0 + ko, ab);
    gld16(agp1 + ko, ab + 512);
    gld16(bgp0 + ko, bb);
    gld16(bgp1 + ko, bb + 512);
  };

  const int nsteps = K >> 5;
  stage(0, 0);
  for (int ks = 0; ks < nsteps; ++ks) {
    const int cur = ks & 1;
    __syncthreads();  // drains vmcnt -> tile `cur` ready; prior reads done
    if (ks + 1 < nsteps) stage(ks + 1, cur ^ 1);
    bf16x8 af[4], bfr[4];
#pragma unroll
    for (int m = 0; m < 4; m++)
      af[m] = *reinterpret_cast<const bf16x8*>(
          &As[cur][(wr * 64 + m * 16 + lr) * 32 + g * 8]);
#pragma unroll
    for (int n = 0; n < 4; n++)
      bfr[n] = *reinterpret_cast<const bf16x8*>(
          &Bs[cur][(wc * 64 + n * 16 + lr) * 32 + g * 8]);
#pragma unroll
    for (int m = 0; m < 4; m++)
#pragma unroll
      for (int n = 0; n < 4; n++) acc[m][n] = mfma16(af[m], bfr[n], acc[m][n]);
  }

  const int crow0 = m0 + wr * 64;
  const int ccol0 = n0 + wc * 64;

  if constexpr (EPI == 0) {
    u16* C16 = (u16*)Cb + (size_t)czoff;
#pragma unroll
    for (int n = 0; n < 4; n++) {
      const int col = ccol0 + n * 16 + lr;
      const float bv = bias[col];
#pragma unroll
      for (int m = 0; m < 4; m++)
#pragma unroll
        for (int j = 0; j < 4; j++) {
          const int row = crow0 + m * 16 + (g << 2) + j;
          C16[(size_t)row * ldc + col] = f2bf(acc[m][n][j] + bv);
        }
    }
  } else if constexpr (EPI == 1 || EPI == 4) {
    float* C32 = (float*)Cb + (size_t)czoff;
#pragma unroll
    for (int n = 0; n < 4; n++) {
      const int col = ccol0 + n * 16 + lr;
      const float bv = (EPI == 1) ? bias[col] : 0.0f;
#pragma unroll
      for (int m = 0; m < 4; m++)
#pragma unroll
        for (int j = 0; j < 4; j++) {
          const int row = crow0 + m * 16 + (g << 2) + j;
          float v = acc[m][n][j] + bv;
          if constexpr (EPI == 4) v += C32[(size_t)row * ldc + col];
          C32[(size_t)row * ldc + col] = v;
        }
    }
  } else if constexpr (EPI == 2) {
    u16* C16 = (u16*)Cb + (size_t)czoff;
#pragma unroll
    for (int m = 0; m < 4; m++) {
      float rsum[4] = {0.f, 0.f, 0.f, 0.f};
#pragma unroll
      for (int n = 0; n < 4; n++) {
        const int col = ccol0 + n * 16 + lr;
#pragma unroll
        for (int j = 0; j < 4; j++) {
          const float p = __expf(acc[m][n][j] * kScale);
          const u16 pb = f2bf(p);
          C16[(size_t)(crow0 + m * 16 + (g << 2) + j) * ldc + col] = pb;
          rsum[j] += bf2f(pb);  // keep l consistent with stored bf16 P
        }
      }
#pragma unroll
      for (int j = 0; j < 4; j++) {
        float r = rsum[j];
        r += __shfl_xor(r, 1, 64);
        r += __shfl_xor(r, 2, 64);
        r += __shfl_xor(r, 4, 64);
        r += __shfl_xor(r, 8, 64);
        if (lr == 0) atomicAdd(&lrow[crow0 + m * 16 + (g << 2) + j], r);
      }
    }
  } else if constexpr (EPI == 3) {
    u16* C16 = (u16*)Cb + (size_t)czoff;
#pragma unroll
    for (int m = 0; m < 4; m++)
#pragma unroll
      for (int j = 0; j < 4; j++) {
        const int row = crow0 + m * 16 + (g << 2) + j;
        const float inv = 1.0f / lrow[row];
#pragma unroll
        for (int n = 0; n < 4; n++) {
          const int col = ccol0 + n * 16 + lr;
          C16[(size_t)row * ldc + col] = f2bf(acc[m][n][j] * inv);
        }
      }
  } else if constexpr (EPI == 5) {
    // V-projection: C rows are sequence positions s (within batch b),
    // C cols are (h,d). Write transposed into VT[z=b*8+h][d][s] via an
    // LDS-staged tile so global stores are 16B-coalesced along s.
    __shared__ __align__(16) u16 T[128 * 136];  // [d_local][s_local], pad 8
#pragma unroll
    for (int n = 0; n < 4; n++) {
      const int cl = wc * 64 + n * 16 + lr;  // col_local = d_local
      const float bv = bias[n0 + cl];
#pragma unroll
      for (int m = 0; m < 4; m++) {
        const int rl = wr * 64 + m * 16 + (g << 2);  // row_local = s_local
#pragma unroll
        for (int j = 0; j < 4; j++)
          T[cl * 136 + rl + j] = f2bf(acc[m][n][j] + bv);
      }
    }
    __syncthreads();
    const int zb = ((m0 >> 11) << 3) + (n0 >> 9);  // b*8 + h
    u16* VT = (u16*)Cb + (size_t)zb * kD * kS + (size_t)(n0 & 511) * kS +
              (m0 & 2047);
#pragma unroll
    for (int p = 0; p < 8; p++) {
      const int dl = p * 16 + (tid >> 4);
      const int s0 = (tid & 15) << 3;
      *reinterpret_cast<uint4*>(VT + (size_t)dl * kS + s0) =
          *reinterpret_cast<const uint4*>(&T[dl * 136 + s0]);
    }
  }
}

extern "C" void kernel_launch(void* const* d_in, const int* in_sizes, int n_in,
                              void* d_out, int out_size, void* d_ws,
                              size_t ws_size, hipStream_t stream) {
  const float* x = (const float*)d_in[0];
  const float* ln_w = (const float*)d_in[1];
  const float* ln_b = (const float*)d_in[2];
  const float* q_w = (const float*)d_in[3];
  const float* q_b = (const float*)d_in[4];
  const float* k_w = (const float*)d_in[5];
  const float* k_b = (const float*)d_in[6];
  const float* v_w = (const float*)d_in[7];
  const float* v_b = (const float*)d_in[8];
  const float* o_w = (const float*)d_in[9];
  const float* o_b = (const float*)d_in[10];
  float* out = (float*)d_out;

  // ---- workspace plan, adaptive to ws_size ----
  constexpr size_t SZ_XN = (size_t)kBS * kD * 2;        // 8 MB
  constexpr size_t SZ_QKVT = (size_t)kNQKV * kD * 2;    // 12 MB
  constexpr size_t SZ_OWT = (size_t)kND * kD * 2;       // 4 MB
  constexpr size_t SZ_CB = (size_t)kNQK * 4;            // 32 KB
  constexpr size_t SZ_LB = (size_t)32 * kS * 4;         // 256 KB
  constexpr size_t SZ_QK = (size_t)kBS * kNQK * 2;      // 128 MB
  constexpr size_t SZ_VT = (size_t)32 * kD * kS * 2;    // 64 MB
  constexpr size_t SZ_AO = (size_t)kBS * kND * 2;       // 64 MB
  constexpr size_t SZ_S = (size_t)kS * kS * 2;          // 8 MB per z
  constexpr size_t SZ_H = (size_t)kBS * kD * 2;         // 8 MB per head
  constexpr size_t SZ_BH = (size_t)kS * kD * 2;         // 2 MB per (b,h)
  const size_t common = SZ_XN + SZ_QKVT + SZ_OWT + SZ_CB + SZ_LB;

  char* p = (char*)d_ws;
  auto alloc = [&](size_t bytes) {
    char* r = p;
    p += (bytes + 255) & ~(size_t)255;
    return r;
  };
  auto fits = [&](size_t extra) { return common + extra + 4096 <= ws_size; };

  const size_t fusedExtra = SZ_QK + SZ_VT + SZ_AO;  // 256 MB
  int plan, zc;
  if (fits(fusedExtra + 16 * SZ_S)) { plan = 0; zc = 16; }
  else if (fits(fusedExtra + 8 * SZ_S)) { plan = 0; zc = 8; }
  else if (fits(fusedExtra + 4 * SZ_S)) { plan = 0; zc = 4; }
  else if (fits(fusedExtra + 2 * SZ_S)) { plan = 0; zc = 2; }
  else if (fits(fusedExtra + 1 * SZ_S)) { plan = 0; zc = 1; }
  else if (fits(4 * SZ_H + SZ_AO + 4 * SZ_S)) { plan = 1; zc = 4; }
  else if (fits(4 * SZ_H + SZ_AO + 1 * SZ_S)) { plan = 1; zc = 1; }
  else if (fits(5 * SZ_H + 4 * SZ_S)) { plan = 2; zc = 4; }
  else if (fits(5 * SZ_H + 1 * SZ_S)) { plan = 2; zc = 1; }
  else { plan = 3; zc = 1; }

  u16* xn = (u16*)alloc(SZ_XN);
  u16* qkvT = (u16*)alloc(SZ_QKVT);  // q rows [0,4096), k [4096,8192), v [8192,12288)
  u16* owT = (u16*)alloc(SZ_OWT);
  float* cbias = (float*)alloc(SZ_CB);
  float* lbuf = (float*)alloc(SZ_LB);

  u16* kwT = qkvT + (size_t)kND * kD;
  u16* vwT = qkvT + (size_t)2 * kND * kD;

  // ---- common pre-work ----
  k_zero<<<dim3(256), 256, 0, stream>>>(lbuf, 32 * kS);
  k_ln<<<dim3(kBS / 4), 256, 0, stream>>>(x, ln_w, ln_b, xn);
  dim3 tb(32, 8);
  k_wt<<<dim3(kND / 32, kD / 32), tb, 0, stream>>>(q_w, qkvT, kD, kND);
  k_wt<<<dim3(kND / 32, kD / 32), tb, 0, stream>>>(k_w, kwT, kD, kND);
  k_wt<<<dim3(kND / 32, kD / 32), tb, 0, stream>>>(v_w, vwT, kD, kND);
  k_wt<<<dim3(kD / 32, kND / 32), tb, 0, stream>>>(o_w, owT, kND, kD);

  const i64 sS = (i64)kS * kS;  // S tile stride (elems)

  if (plan == 0) {
    // ---- fused plan: QK proj + V proj (direct-transposed), z-merged core ----
    u16* QKb = (u16*)alloc(SZ_QK);   // [8192, 8192]: Q|K per row
    u16* VTb = (u16*)alloc(SZ_VT);   // [32][512][2048]
    u16* AOb = (u16*)alloc(SZ_AO);   // [8192, 4096]
    u16* Sb = (u16*)alloc((size_t)zc * SZ_S);

    k_cat2<<<dim3(kNQK / 256), 256, 0, stream>>>(q_b, k_b, cbias);
    // fused QK projection: [8192,512] x [8192,512]^T -> [8192,8192]
    k_gemm<0><<<dim3(kBS / 128, kNQK / 128), 256, 0, stream>>>(
        xn, kD, 0, 0, qkvT, kD, 0, 0, QKb, kNQK, 0, 0, kD, cbias, nullptr, 0);
    // V projection, output written directly transposed into VT
    k_gemm<5><<<dim3(kBS / 128, kND / 128), 256, 0, stream>>>(
        xn, kD, 0, 0, vwT, kD, 0, 0, VTb, 0, 0, 0, kD, v_b, nullptr, 0);

    const u16* Qb = QKb;
    const u16* Kb = QKb + kND;
    const i64 sHiQK = (i64)kS * kNQK - 8 * kD;  // extra jump at b boundary
    const i64 sHiAO = (i64)kS * kND - 8 * kD;
    for (int z0 = 0; z0 < 32; z0 += zc) {
      const i64 qoff = (i64)z0 * kD + (i64)(z0 >> 3) * sHiQK;
      const i64 aoff = (i64)z0 * kD + (i64)(z0 >> 3) * sHiAO;
      float* lr0 = lbuf + (size_t)z0 * kS;
      k_gemm<2><<<dim3(16, 16, zc), 256, 0, stream>>>(
          Qb + qoff, kNQK, kD, sHiQK, Kb + qoff, kNQK, kD, sHiQK, Sb, kS, sS,
          0, kD, nullptr, lr0, kS);
      k_gemm<3><<<dim3(16, 4, zc), 256, 0, stream>>>(
          Sb, kS, sS, 0, VTb + (size_t)z0 * kD * kS, kS, (i64)kD * kS, 0,
          AOb + aoff, kND, kD, sHiAO, kS, nullptr, lr0, kS);
    }
    k_gemm<1><<<dim3(64, 4), 256, 0, stream>>>(AOb, kND, 0, 0, owT, kND, 0, 0,
                                               out, kD, 0, 0, kND, o_b,
                                               nullptr, 0);
  } else if (plan == 1 || plan == 2) {
    u16* Qh = (u16*)alloc(SZ_H);
    u16* Kh = (u16*)alloc(SZ_H);
    u16* Vh = (u16*)alloc(SZ_H);
    u16* VTh = (u16*)alloc(SZ_H);
    u16* AO = (u16*)alloc(plan == 1 ? SZ_AO : SZ_H);
    u16* Sb = (u16*)alloc((size_t)zc * SZ_S);
    const int aold = (plan == 1) ? kND : kD;

    for (int h = 0; h < kH; h++) {
      const u16* qwh = qkvT + (size_t)h * kD * kD;
      const u16* kwh = kwT + (size_t)h * kD * kD;
      const u16* vwh = vwT + (size_t)h * kD * kD;
      k_gemm<0><<<dim3(64, 4), 256, 0, stream>>>(xn, kD, 0, 0, qwh, kD, 0, 0,
                                                 Qh, kD, 0, 0, kD, q_b + h * kD,
                                                 nullptr, 0);
      k_gemm<0><<<dim3(64, 4), 256, 0, stream>>>(xn, kD, 0, 0, kwh, kD, 0, 0,
                                                 Kh, kD, 0, 0, kD, k_b + h * kD,
                                                 nullptr, 0);
      k_gemm<0><<<dim3(64, 4), 256, 0, stream>>>(xn, kD, 0, 0, vwh, kD, 0, 0,
                                                 Vh, kD, 0, 0, kD, v_b + h * kD,
                                                 nullptr, 0);
      k_vt<<<dim3(64, 16, 4), tb, 0, stream>>>(Vh, VTh, kD, (i64)kS * kD, 0,
                                               (i64)kD * kS);
      u16* AOh = (plan == 1) ? AO + (size_t)h * kD : AO;
      const i64 sAO = (plan == 1) ? (i64)kS * kND : (i64)kS * kD;
      for (int b0 = 0; b0 < kB; b0 += zc) {
        float* lr0 = lbuf + (size_t)(h * 4 + b0) * kS;
        k_gemm<2><<<dim3(16, 16, zc), 256, 0, stream>>>(
            Qh + (size_t)b0 * kS * kD, kD, (i64)kS * kD, 0,
            Kh + (size_t)b0 * kS * kD, kD, (i64)kS * kD, 0, Sb, kS, sS, 0, kD,
            nullptr, lr0, kS);
        k_gemm<3><<<dim3(16, 4, zc), 256, 0, stream>>>(
            Sb, kS, sS, 0, VTh + (size_t)b0 * kD * kS, kS, (i64)kD * kS, 0,
            AOh + (size_t)b0 * kS * aold, aold, sAO, 0, kS, nullptr, lr0, kS);
      }
      if (plan == 2) {
        if (h == 0)
          k_gemm<1><<<dim3(64, 4), 256, 0, stream>>>(
              AO, kD, 0, 0, owT + (size_t)h * kD, kND, 0, 0, out, kD, 0, 0, kD,
              o_b, nullptr, 0);
        else
          k_gemm<4><<<dim3(64, 4), 256, 0, stream>>>(
              AO, kD, 0, 0, owT + (size_t)h * kD, kND, 0, 0, out, kD, 0, 0, kD,
              nullptr, nullptr, 0);
      }
    }
    if (plan == 1)
      k_gemm<1><<<dim3(64, 4), 256, 0, stream>>>(AO, kND, 0, 0, owT, kND, 0, 0,
                                                 out, kD, 0, 0, kND, o_b,
                                                 nullptr, 0);
  } else {
    u16* Qbh = (u16*)alloc(SZ_BH);
    u16* Kbh = (u16*)alloc(SZ_BH);
    u16* Vbh = (u16*)alloc(SZ_BH);
    u16* VTbh = (u16*)alloc(SZ_BH);
    u16* AObh = (u16*)alloc(SZ_BH);
    u16* Sb = (u16*)alloc(SZ_S);

    for (int b = 0; b < kB; b++)
      for (int h = 0; h < kH; h++) {
        const u16* xb = xn + (size_t)b * kS * kD;
        k_gemm<0><<<dim3(16, 4), 256, 0, stream>>>(
            xb, kD, 0, 0, qkvT + (size_t)h * kD * kD, kD, 0, 0, Qbh, kD, 0, 0,
            kD, q_b + h * kD, nullptr, 0);
        k_gemm<0><<<dim3(16, 4), 256, 0, stream>>>(
            xb, kD, 0, 0, kwT + (size_t)h * kD * kD, kD, 0, 0, Kbh, kD, 0, 0,
            kD, k_b + h * kD, nullptr, 0);
        k_gemm<0><<<dim3(16, 4), 256, 0, stream>>>(
            xb, kD, 0, 0, vwT + (size_t)h * kD * kD, kD, 0, 0, Vbh, kD, 0, 0,
            kD, v_b + h * kD, nullptr, 0);
        k_vt<<<dim3(64, 16, 1), tb, 0, stream>>>(Vbh, VTbh, kD, 0, 0, 0);
        float* lr0 = lbuf + (size_t)(b * 8 + h) * kS;
        k_gemm<2><<<dim3(16, 16, 1), 256, 0, stream>>>(
            Qbh, kD, 0, 0, Kbh, kD, 0, 0, Sb, kS, 0, 0, kD, nullptr, lr0, 0);
        k_gemm<3><<<dim3(16, 4, 1), 256, 0, stream>>>(
            Sb, kS, 0, 0, VTbh, kS, 0, 0, AObh, kD, 0, 0, kS, nullptr, lr0, 0);
        float* outb = out + (size_t)b * kS * kD;
        if (h == 0)
          k_gemm<1><<<dim3(16, 4), 256, 0, stream>>>(
              AObh, kD, 0, 0, owT, kND, 0, 0, outb, kD, 0, 0, kD, o_b, nullptr,
              0);
        else
          k_gemm<4><<<dim3(16, 4), 256, 0, stream>>>(
              AObh, kD, 0, 0, owT + (size_t)h * kD, kND, 0, 0, outb, kD, 0, 0,
              kD, nullptr, nullptr, 0);
      }
  }
}

// Round 4
// 947.581 us; speedup vs baseline: 1.1603x; 1.1493x over previous
//
#include <hip/hip_runtime.h>

typedef unsigned short u16;
typedef unsigned int u32;
typedef long long i64;
typedef __attribute__((ext_vector_type(4))) float f32x4;
typedef __attribute__((ext_vector_type(8))) __bf16 bf16x8;

#define DEVI static __device__ __forceinline__

constexpr int kB = 4, kS = 2048, kD = 512, kH = 8;
constexpr int kND = kD * kH;     // 4096
constexpr int kBS = kB * kS;     // 8192
constexpr int kNQK = 2 * kND;    // 8192
constexpr int kNQKV = 3 * kND;   // 12288
constexpr float kScale = 0.044194173824159216f;  // 512^-0.5

DEVI u16 f2bf(float f) {
  u32 u = __builtin_bit_cast(u32, f);
  return (u16)((u + 0x7fffu + ((u >> 16) & 1u)) >> 16);
}
DEVI float bf2f(u16 h) { return __builtin_bit_cast(float, (u32)h << 16); }

DEVI f32x4 mfma16(bf16x8 a, bf16x8 b, f32x4 c) {
  return __builtin_amdgcn_mfma_f32_16x16x32_bf16(a, b, c, 0, 0, 0);
}

// global -> LDS direct DMA, 16B per lane (wave-uniform LDS base + lane*16)
DEVI void gld16(const u16* g, u16* l) {
  __builtin_amdgcn_global_load_lds(
      (const __attribute__((address_space(1))) void*)g,
      (__attribute__((address_space(3))) void*)l, 16, 0, 0);
}

__global__ void k_zero(float* __restrict__ p, int n) {
  int i = blockIdx.x * 256 + threadIdx.x;
  if (i < n) p[i] = 0.0f;
}

// concat q_b|k_b -> [8192] (cols of the fused QK projection)
__global__ void k_cat2(const float* __restrict__ a, const float* __restrict__ b,
                       float* __restrict__ o) {
  int i = blockIdx.x * 256 + threadIdx.x;
  if (i < kND) o[i] = a[i];
  else if (i < 2 * kND) o[i] = b[i - kND];
}

// sum 4 split-K partial planes + bias -> fp32 out [8192,512]
__global__ __launch_bounds__(256) void k_red4(const float* __restrict__ p,
                                              const float* __restrict__ bias,
                                              float* __restrict__ out) {
  const int i = blockIdx.x * 256 + threadIdx.x;  // float4 index
  constexpr int NP = kBS * kD / 4;               // 1048576
  const float4* pv = reinterpret_cast<const float4*>(p);
  const float4 a = pv[i], b = pv[i + NP], c = pv[i + 2 * NP],
               d = pv[i + 3 * NP];
  const float4 bv = reinterpret_cast<const float4*>(bias)[i & 127];
  float4 r;
  r.x = a.x + b.x + c.x + d.x + bv.x;
  r.y = a.y + b.y + c.y + d.y + bv.y;
  r.z = a.z + b.z + c.z + d.z + bv.z;
  r.w = a.w + b.w + c.w + d.w + bv.w;
  reinterpret_cast<float4*>(out)[i] = r;
}

// ---------------- LayerNorm: fp32 [8192,512] -> bf16 xn ----------------
__global__ __launch_bounds__(256) void k_ln(const float* __restrict__ x,
                                            const float* __restrict__ lw,
                                            const float* __restrict__ lb,
                                            u16* __restrict__ xn) {
  const int lane = threadIdx.x & 63;
  const int row = (blockIdx.x << 2) + (threadIdx.x >> 6);
  const float4* xp = reinterpret_cast<const float4*>(x + (size_t)row * kD);
  float4 a = xp[lane * 2], b = xp[lane * 2 + 1];
  float s = a.x + a.y + a.z + a.w + b.x + b.y + b.z + b.w;
  float ss = a.x * a.x + a.y * a.y + a.z * a.z + a.w * a.w +
             b.x * b.x + b.y * b.y + b.z * b.z + b.w * b.w;
#pragma unroll
  for (int m = 1; m < 64; m <<= 1) {
    s += __shfl_xor(s, m, 64);
    ss += __shfl_xor(ss, m, 64);
  }
  const float mean = s * (1.0f / kD);
  const float var = ss * (1.0f / kD) - mean * mean;
  const float rstd = rsqrtf(fmaxf(var, 0.0f) + 1e-5f);
  const float4* wp = reinterpret_cast<const float4*>(lw);
  const float4* bp = reinterpret_cast<const float4*>(lb);
  float4 w0 = wp[lane * 2], w1 = wp[lane * 2 + 1];
  float4 b0 = bp[lane * 2], b1 = bp[lane * 2 + 1];
  float o0 = (a.x - mean) * rstd * w0.x + b0.x;
  float o1 = (a.y - mean) * rstd * w0.y + b0.y;
  float o2 = (a.z - mean) * rstd * w0.z + b0.z;
  float o3 = (a.w - mean) * rstd * w0.w + b0.w;
  float o4 = (b.x - mean) * rstd * w1.x + b1.x;
  float o5 = (b.y - mean) * rstd * w1.y + b1.y;
  float o6 = (b.z - mean) * rstd * w1.z + b1.z;
  float o7 = (b.w - mean) * rstd * w1.w + b1.w;
  uint4 st = make_uint4((u32)f2bf(o0) | ((u32)f2bf(o1) << 16),
                        (u32)f2bf(o2) | ((u32)f2bf(o3) << 16),
                        (u32)f2bf(o4) | ((u32)f2bf(o5) << 16),
                        (u32)f2bf(o6) | ((u32)f2bf(o7) << 16));
  *reinterpret_cast<uint4*>(xn + (size_t)row * kD + lane * 8) = st;
}

// ------------- weight transpose: fp32 [R,C] -> bf16 [C,R] -------------
__global__ void k_wt(const float* __restrict__ in, u16* __restrict__ out,
                     int R, int C) {
  __shared__ float t[32][33];
  const int tx = threadIdx.x, ty = threadIdx.y;
  const int c0 = blockIdx.x << 5, r0 = blockIdx.y << 5;
#pragma unroll
  for (int i = 0; i < 4; i++)
    t[ty + 8 * i][tx] = in[(size_t)(r0 + ty + 8 * i) * C + c0 + tx];
  __syncthreads();
#pragma unroll
  for (int i = 0; i < 4; i++)
    out[(size_t)(c0 + ty + 8 * i) * R + r0 + tx] = f2bf(t[tx][ty + 8 * i]);
}

// ------- V transpose: bf16 V[2048, d-slice] -> VT[z][512][2048] -------
// (used only by fallback plans 1-3)
__global__ void k_vt(const u16* __restrict__ V, u16* __restrict__ VT, int ldv,
                     i64 sVz, i64 sVzH, i64 sTz) {
  const int z = blockIdx.z;
  V += (size_t)((i64)z * sVz + (i64)(z >> 3) * sVzH);
  VT += (size_t)((i64)z * sTz);
  __shared__ u16 t[32][33];
  const int tx = threadIdx.x, ty = threadIdx.y;
  const int s0 = blockIdx.x << 5, d0 = blockIdx.y << 5;
#pragma unroll
  for (int i = 0; i < 4; i++)
    t[ty + 8 * i][tx] = V[(size_t)(s0 + ty + 8 * i) * ldv + d0 + tx];
  __syncthreads();
#pragma unroll
  for (int i = 0; i < 4; i++)
    VT[(size_t)(d0 + ty + 8 * i) * kS + s0 + tx] = t[tx][ty + 8 * i];
}

// ---------------- GEMM: C[M,N] = A[M,K] * Bt[N,K]^T (+epilogue) -------
// m97-style: global_load_lds(16B) staging, double-buffered LDS,
// ONE barrier per K-step (stage k+1 into buf^1 while MFMA-ing buf).
// z offsets decomposed as z*s + (z>>3)*sH so one launch can span all
// (b,h) pairs even when batch stride != 8*head stride.
// EPI 0: bf16 out + bias                                    (QK proj)
// EPI 1: f32  out + bias                                    (O-proj, plans 1-3)
// EPI 4: f32  out += acc                                    (O-proj accum)
// EPI 2: bf16 out = exp(acc*scale), atomic row-sums -> lrow (QK^T)
// EPI 3: bf16 out = acc / lrow[row]                          (P@V)
// EPI 5: V-proj: bf16 (acc+bias) written TRANSPOSED into VT[z][d][s]
// EPI 6: f32 partial out (split-K plane per z)               (O-proj)
template <int EPI>
__global__ __launch_bounds__(256) void k_gemm(
    const u16* __restrict__ A, int lda, i64 sAz, i64 sAzH,
    const u16* __restrict__ Bt, int ldb, i64 sBz, i64 sBzH,
    void* __restrict__ Cb, int ldc, i64 sCz, i64 sCzH, int K,
    const float* __restrict__ bias, float* __restrict__ lbase, i64 sLz) {
  const int z = blockIdx.z;
  A += (size_t)((i64)z * sAz + (i64)(z >> 3) * sAzH);
  Bt += (size_t)((i64)z * sBz + (i64)(z >> 3) * sBzH);
  const i64 czoff = (i64)z * sCz + (i64)(z >> 3) * sCzH;
  float* lrow = lbase + (size_t)z * sLz;

  // unified LDS: [0..1]=A dbuf, [2..3]=B dbuf (gload_lds needs linear dest).
  // EPI 5 reuses the whole 32KB as a 128x128 transpose tile after the loop.
  __shared__ __align__(16) u16 smem[4][128 * 32];

  const int tid = threadIdx.x;
  const int lane = tid & 63, wid = tid >> 6;
  const int g = lane >> 4, lr = lane & 15;
  const int wr = wid >> 1, wc = wid & 1;
  const int m0 = blockIdx.x << 7, n0 = blockIdx.y << 7;

  // staging geometry: wave w covers rows [32w,32w+32) of the tile in two
  // 1KB chunks; lane l -> row 32w+(l>>2) (+16 for chunk 1), col (l&3)*8
  const int srow = (wid << 5) + (lane >> 2);
  const int scol = (lane & 3) << 3;
  const u16* agp0 = A + (size_t)(m0 + srow) * lda + scol;
  const u16* agp1 = A + (size_t)(m0 + srow + 16) * lda + scol;
  const u16* bgp0 = Bt + (size_t)(n0 + srow) * ldb + scol;
  const u16* bgp1 = Bt + (size_t)(n0 + srow + 16) * ldb + scol;

  f32x4 acc[4][4] = {};

  auto stage = [&](int ks, int buf) {
    const int ko = ks << 5;
    u16* ab = &smem[buf][wid << 10];  // wave-uniform chunk base
    u16* bb = &smem[2 + buf][wid << 10];
    gld16(agp0 + ko, ab);
    gld16(agp1 + ko, ab + 512);
    gld16(bgp0 + ko, bb);
    gld16(bgp1 + ko, bb + 512);
  };

  const int nsteps = K >> 5;
  stage(0, 0);
  for (int ks = 0; ks < nsteps; ++ks) {
    const int cur = ks & 1;
    __syncthreads();  // drains vmcnt -> tile `cur` ready; prior reads done
    if (ks + 1 < nsteps) stage(ks + 1, cur ^ 1);
    bf16x8 af[4], bfr[4];
#pragma unroll
    for (int m = 0; m < 4; m++)
      af[m] = *reinterpret_cast<const bf16x8*>(
          &smem[cur][(wr * 64 + m * 16 + lr) * 32 + g * 8]);
#pragma unroll
    for (int n = 0; n < 4; n++)
      bfr[n] = *reinterpret_cast<const bf16x8*>(
          &smem[2 + cur][(wc * 64 + n * 16 + lr) * 32 + g * 8]);
#pragma unroll
    for (int m = 0; m < 4; m++)
#pragma unroll
      for (int n = 0; n < 4; n++) acc[m][n] = mfma16(af[m], bfr[n], acc[m][n]);
  }

  const int crow0 = m0 + wr * 64;
  const int ccol0 = n0 + wc * 64;

  if constexpr (EPI == 0) {
    u16* C16 = (u16*)Cb + (size_t)czoff;
#pragma unroll
    for (int n = 0; n < 4; n++) {
      const int col = ccol0 + n * 16 + lr;
      const float bv = bias[col];
#pragma unroll
      for (int m = 0; m < 4; m++)
#pragma unroll
        for (int j = 0; j < 4; j++) {
          const int row = crow0 + m * 16 + (g << 2) + j;
          C16[(size_t)row * ldc + col] = f2bf(acc[m][n][j] + bv);
        }
    }
  } else if constexpr (EPI == 1 || EPI == 4 || EPI == 6) {
    float* C32 = (float*)Cb + (size_t)czoff;
#pragma unroll
    for (int n = 0; n < 4; n++) {
      const int col = ccol0 + n * 16 + lr;
      const float bv = (EPI == 1) ? bias[col] : 0.0f;
#pragma unroll
      for (int m = 0; m < 4; m++)
#pragma unroll
        for (int j = 0; j < 4; j++) {
          const int row = crow0 + m * 16 + (g << 2) + j;
          float v = acc[m][n][j] + bv;
          if constexpr (EPI == 4) v += C32[(size_t)row * ldc + col];
          C32[(size_t)row * ldc + col] = v;
        }
    }
  } else if constexpr (EPI == 2) {
    u16* C16 = (u16*)Cb + (size_t)czoff;
#pragma unroll
    for (int m = 0; m < 4; m++) {
      float rsum[4] = {0.f, 0.f, 0.f, 0.f};
#pragma unroll
      for (int n = 0; n < 4; n++) {
        const int col = ccol0 + n * 16 + lr;
#pragma unroll
        for (int j = 0; j < 4; j++) {
          const float p = __expf(acc[m][n][j] * kScale);
          const u16 pb = f2bf(p);
          C16[(size_t)(crow0 + m * 16 + (g << 2) + j) * ldc + col] = pb;
          rsum[j] += bf2f(pb);  // keep l consistent with stored bf16 P
        }
      }
#pragma unroll
      for (int j = 0; j < 4; j++) {
        float r = rsum[j];
        r += __shfl_xor(r, 1, 64);
        r += __shfl_xor(r, 2, 64);
        r += __shfl_xor(r, 4, 64);
        r += __shfl_xor(r, 8, 64);
        if (lr == 0) atomicAdd(&lrow[crow0 + m * 16 + (g << 2) + j], r);
      }
    }
  } else if constexpr (EPI == 3) {
    u16* C16 = (u16*)Cb + (size_t)czoff;
#pragma unroll
    for (int m = 0; m < 4; m++)
#pragma unroll
      for (int j = 0; j < 4; j++) {
        const int row = crow0 + m * 16 + (g << 2) + j;
        const float inv = 1.0f / lrow[row];
#pragma unroll
        for (int n = 0; n < 4; n++) {
          const int col = ccol0 + n * 16 + lr;
          C16[(size_t)row * ldc + col] = f2bf(acc[m][n][j] * inv);
        }
      }
  } else if constexpr (EPI == 5) {
    // V-proj: write transposed into VT[z][d][s]. Reuse the main 32KB LDS
    // (dead after the K-loop) as a 128x128 bf16 tile with an 8-element XOR
    // swizzle: elem (cl,rl) at cl*128 + (((rl>>3)^(cl&7))<<3 | (rl&7)).
    // Round trip: row cl=dl, block r8 -> rl = (r8^(dl&7))... inverse of read
    // index, giving 16B-contiguous conflict-free reads.
    u16* T = &smem[0][0];
    __syncthreads();  // all waves done reading K-loop buffers
#pragma unroll
    for (int n = 0; n < 4; n++) {
      const int cl = wc * 64 + n * 16 + lr;  // d_local
      const float bv = bias[n0 + cl];
#pragma unroll
      for (int m = 0; m < 4; m++) {
        const int rlb = wr * 64 + m * 16 + (g << 2);  // s_local base
#pragma unroll
        for (int j = 0; j < 4; j++) {
          const int rl = rlb + j;
          T[cl * 128 + ((((rl >> 3) ^ (cl & 7)) << 3) | (rl & 7))] =
              f2bf(acc[m][n][j] + bv);
        }
      }
    }
    __syncthreads();
    const int zb = ((m0 >> 11) << 3) + (n0 >> 9);  // b*8 + h
    u16* VT = (u16*)Cb + (size_t)zb * kD * kS + (size_t)(n0 & 511) * kS +
              (m0 & 2047);
#pragma unroll
    for (int p = 0; p < 8; p++) {
      const int dl = p * 16 + (tid >> 4);
      const int r8 = tid & 15;
      *reinterpret_cast<uint4*>(VT + (size_t)dl * kS + (r8 << 3)) =
          *reinterpret_cast<const uint4*>(
              &T[dl * 128 + ((r8 ^ (dl & 7)) << 3)]);
    }
  }
}

extern "C" void kernel_launch(void* const* d_in, const int* in_sizes, int n_in,
                              void* d_out, int out_size, void* d_ws,
                              size_t ws_size, hipStream_t stream) {
  const float* x = (const float*)d_in[0];
  const float* ln_w = (const float*)d_in[1];
  const float* ln_b = (const float*)d_in[2];
  const float* q_w = (const float*)d_in[3];
  const float* q_b = (const float*)d_in[4];
  const float* k_w = (const float*)d_in[5];
  const float* k_b = (const float*)d_in[6];
  const float* v_w = (const float*)d_in[7];
  const float* v_b = (const float*)d_in[8];
  const float* o_w = (const float*)d_in[9];
  const float* o_b = (const float*)d_in[10];
  float* out = (float*)d_out;

  // ---- workspace plan, adaptive to ws_size ----
  constexpr size_t SZ_XN = (size_t)kBS * kD * 2;        // 8 MB
  constexpr size_t SZ_QKVT = (size_t)kNQKV * kD * 2;    // 12 MB
  constexpr size_t SZ_OWT = (size_t)kND * kD * 2;       // 4 MB
  constexpr size_t SZ_CB = (size_t)kNQK * 4;            // 32 KB
  constexpr size_t SZ_LB = (size_t)32 * kS * 4;         // 256 KB
  constexpr size_t SZ_QK = (size_t)kBS * kNQK * 2;      // 128 MB (AO aliases)
  constexpr size_t SZ_VT = (size_t)32 * kD * kS * 2;    // 64 MB
  constexpr size_t SZ_AO = (size_t)kBS * kND * 2;       // 64 MB
  constexpr size_t SZ_S = (size_t)kS * kS * 2;          // 8 MB per z
  constexpr size_t SZ_H = (size_t)kBS * kD * 2;         // 8 MB per head
  constexpr size_t SZ_BH = (size_t)kS * kD * 2;         // 2 MB per (b,h)
  const size_t common = SZ_XN + SZ_QKVT + SZ_OWT + SZ_CB + SZ_LB;

  char* p = (char*)d_ws;
  auto alloc = [&](size_t bytes) {
    char* r = p;
    p += (bytes + 255) & ~(size_t)255;
    return r;
  };
  auto fits = [&](size_t extra) { return common + extra + 4096 <= ws_size; };

  // plan 0: AO aliases the QK buffer (valid for zc multiple of 8: PV(batch b)
  // writes AO bytes [16b,16b+16)MB; later QK^T(batch b'>b) reads QK bytes
  // [32b',32b'+32)MB -- disjoint since 16(b+1) <= 32b').
  const size_t fusedExtra = SZ_QK + SZ_VT;  // 192 MB
  int plan, zc;
  if (fits(fusedExtra + 32 * SZ_S)) { plan = 0; zc = 32; }
  else if (fits(fusedExtra + 16 * SZ_S)) { plan = 0; zc = 16; }
  else if (fits(fusedExtra + 8 * SZ_S)) { plan = 0; zc = 8; }
  else if (fits(4 * SZ_H + SZ_AO + 4 * SZ_S)) { plan = 1; zc = 4; }
  else if (fits(4 * SZ_H + SZ_AO + 1 * SZ_S)) { plan = 1; zc = 1; }
  else if (fits(5 * SZ_H + 4 * SZ_S)) { plan = 2; zc = 4; }
  else if (fits(5 * SZ_H + 1 * SZ_S)) { plan = 2; zc = 1; }
  else { plan = 3; zc = 1; }

  u16* xn = (u16*)alloc(SZ_XN);
  u16* qkvT = (u16*)alloc(SZ_QKVT);  // q rows [0,4096), k [4096,8192), v [8192,12288)
  u16* owT = (u16*)alloc(SZ_OWT);
  float* cbias = (float*)alloc(SZ_CB);
  float* lbuf = (float*)alloc(SZ_LB);

  u16* kwT = qkvT + (size_t)kND * kD;
  u16* vwT = qkvT + (size_t)2 * kND * kD;

  // ---- common pre-work ----
  k_zero<<<dim3(256), 256, 0, stream>>>(lbuf, 32 * kS);
  k_ln<<<dim3(kBS / 4), 256, 0, stream>>>(x, ln_w, ln_b, xn);
  dim3 tb(32, 8);
  k_wt<<<dim3(kND / 32, kD / 32), tb, 0, stream>>>(q_w, qkvT, kD, kND);
  k_wt<<<dim3(kND / 32, kD / 32), tb, 0, stream>>>(k_w, kwT, kD, kND);
  k_wt<<<dim3(kND / 32, kD / 32), tb, 0, stream>>>(v_w, vwT, kD, kND);
  k_wt<<<dim3(kD / 32, kND / 32), tb, 0, stream>>>(o_w, owT, kND, kD);

  const i64 sS = (i64)kS * kS;  // S tile stride (elems)

  if (plan == 0) {
    // ---- fused plan: QK proj, V proj (direct-transposed), z-merged core,
    //      AO aliased into QK buffer, split-K O-proj with partials in Sb ----
    u16* QKb = (u16*)alloc(SZ_QK);   // [8192, 8192]: Q|K per row
    u16* VTb = (u16*)alloc(SZ_VT);   // [32][512][2048]
    u16* Sb = (u16*)alloc((size_t)zc * SZ_S);
    u16* AOb = QKb;                  // [8192, 4096] alias (ordering-safe)
    float* Pb = (float*)Sb;          // 4x f32 partial planes (64MB), post-PV

    k_cat2<<<dim3(kNQK / 256), 256, 0, stream>>>(q_b, k_b, cbias);
    // fused QK projection: [8192,512] x [8192,512]^T -> [8192,8192]
    k_gemm<0><<<dim3(kBS / 128, kNQK / 128), 256, 0, stream>>>(
        xn, kD, 0, 0, qkvT, kD, 0, 0, QKb, kNQK, 0, 0, kD, cbias, nullptr, 0);
    // V projection, output written directly transposed into VT
    k_gemm<5><<<dim3(kBS / 128, kND / 128), 256, 0, stream>>>(
        xn, kD, 0, 0, vwT, kD, 0, 0, VTb, 0, 0, 0, kD, v_b, nullptr, 0);

    const u16* Qb = QKb;
    const u16* Kb = QKb + kND;
    const i64 sHiQK = (i64)kS * kNQK - 8 * kD;  // extra jump at b boundary
    const i64 sHiAO = (i64)kS * kND - 8 * kD;
    for (int z0 = 0; z0 < 32; z0 += zc) {
      const i64 qoff = (i64)z0 * kD + (i64)(z0 >> 3) * sHiQK;
      const i64 aoff = (i64)z0 * kD + (i64)(z0 >> 3) * sHiAO;
      float* lr0 = lbuf + (size_t)z0 * kS;
      k_gemm<2><<<dim3(16, 16, zc), 256, 0, stream>>>(
          Qb + qoff, kNQK, kD, sHiQK, Kb + qoff, kNQK, kD, sHiQK, Sb, kS, sS,
          0, kD, nullptr, lr0, kS);
      k_gemm<3><<<dim3(16, 4, zc), 256, 0, stream>>>(
          Sb, kS, sS, 0, VTb + (size_t)z0 * kD * kS, kS, (i64)kD * kS, 0,
          AOb + aoff, kND, kD, sHiAO, kS, nullptr, lr0, kS);
    }
    // O-projection, split-K=4 via z (K=1024 each), partials -> Pb
    k_gemm<6><<<dim3(64, 4, 4), 256, 0, stream>>>(
        AOb, kND, 1024, 0, owT, kND, 1024, 0, Pb, kD, (i64)kBS * kD, 0, 1024,
        nullptr, nullptr, 0);
    k_red4<<<dim3(kBS * kD / 4 / 256), 256, 0, stream>>>(Pb, o_b, out);
  } else if (plan == 1 || plan == 2) {
    u16* Qh = (u16*)alloc(SZ_H);
    u16* Kh = (u16*)alloc(SZ_H);
    u16* Vh = (u16*)alloc(SZ_H);
    u16* VTh = (u16*)alloc(SZ_H);
    u16* AO = (u16*)alloc(plan == 1 ? SZ_AO : SZ_H);
    u16* Sb = (u16*)alloc((size_t)zc * SZ_S);
    const int aold = (plan == 1) ? kND : kD;

    for (int h = 0; h < kH; h++) {
      const u16* qwh = qkvT + (size_t)h * kD * kD;
      const u16* kwh = kwT + (size_t)h * kD * kD;
      const u16* vwh = vwT + (size_t)h * kD * kD;
      k_gemm<0><<<dim3(64, 4), 256, 0, stream>>>(xn, kD, 0, 0, qwh, kD, 0, 0,
                                                 Qh, kD, 0, 0, kD, q_b + h * kD,
                                                 nullptr, 0);
      k_gemm<0><<<dim3(64, 4), 256, 0, stream>>>(xn, kD, 0, 0, kwh, kD, 0, 0,
                                                 Kh, kD, 0, 0, kD, k_b + h * kD,
                                                 nullptr, 0);
      k_gemm<0><<<dim3(64, 4), 256, 0, stream>>>(xn, kD, 0, 0, vwh, kD, 0, 0,
                                                 Vh, kD, 0, 0, kD, v_b + h * kD,
                                                 nullptr, 0);
      k_vt<<<dim3(64, 16, 4), tb, 0, stream>>>(Vh, VTh, kD, (i64)kS * kD, 0,
                                               (i64)kD * kS);
      u16* AOh = (plan == 1) ? AO + (size_t)h * kD : AO;
      const i64 sAO = (plan == 1) ? (i64)kS * kND : (i64)kS * kD;
      for (int b0 = 0; b0 < kB; b0 += zc) {
        float* lr0 = lbuf + (size_t)(h * 4 + b0) * kS;
        k_gemm<2><<<dim3(16, 16, zc), 256, 0, stream>>>(
            Qh + (size_t)b0 * kS * kD, kD, (i64)kS * kD, 0,
            Kh + (size_t)b0 * kS * kD, kD, (i64)kS * kD, 0, Sb, kS, sS, 0, kD,
            nullptr, lr0, kS);
        k_gemm<3><<<dim3(16, 4, zc), 256, 0, stream>>>(
            Sb, kS, sS, 0, VTh + (size_t)b0 * kD * kS, kS, (i64)kD * kS, 0,
            AOh + (size_t)b0 * kS * aold, aold, sAO, 0, kS, nullptr, lr0, kS);
      }
      if (plan == 2) {
        if (h == 0)
          k_gemm<1><<<dim3(64, 4), 256, 0, stream>>>(
              AO, kD, 0, 0, owT + (size_t)h * kD, kND, 0, 0, out, kD, 0, 0, kD,
              o_b, nullptr, 0);
        else
          k_gemm<4><<<dim3(64, 4), 256, 0, stream>>>(
              AO, kD, 0, 0, owT + (size_t)h * kD, kND, 0, 0, out, kD, 0, 0, kD,
              nullptr, nullptr, 0);
      }
    }
    if (plan == 1)
      k_gemm<1><<<dim3(64, 4), 256, 0, stream>>>(AO, kND, 0, 0, owT, kND, 0, 0,
                                                 out, kD, 0, 0, kND, o_b,
                                                 nullptr, 0);
  } else {
    u16* Qbh = (u16*)alloc(SZ_BH);
    u16* Kbh = (u16*)alloc(SZ_BH);
    u16* Vbh = (u16*)alloc(SZ_BH);
    u16* VTbh = (u16*)alloc(SZ_BH);
    u16* AObh = (u16*)alloc(SZ_BH);
    u16* Sb = (u16*)alloc(SZ_S);

    for (int b = 0; b < kB; b++)
      for (int h = 0; h < kH; h++) {
        const u16* xb = xn + (size_t)b * kS * kD;
        k_gemm<0><<<dim3(16, 4), 256, 0, stream>>>(
            xb, kD, 0, 0, qkvT + (size_t)h * kD * kD, kD, 0, 0, Qbh, kD, 0, 0,
            kD, q_b + h * kD, nullptr, 0);
        k_gemm<0><<<dim3(16, 4), 256, 0, stream>>>(
            xb, kD, 0, 0, kwT + (size_t)h * kD * kD, kD, 0, 0, Kbh, kD, 0, 0,
            kD, k_b + h * kD, nullptr, 0);
        k_gemm<0><<<dim3(16, 4), 256, 0, stream>>>(
            xb, kD, 0, 0, vwT + (size_t)h * kD * kD, kD, 0, 0, Vbh, kD, 0, 0,
            kD, v_b + h * kD, nullptr, 0);
        k_vt<<<dim3(64, 16, 1), tb, 0, stream>>>(Vbh, VTbh, kD, 0, 0, 0);
        float* lr0 = lbuf + (size_t)(b * 8 + h) * kS;
        k_gemm<2><<<dim3(16, 16, 1), 256, 0, stream>>>(
            Qbh, kD, 0, 0, Kbh, kD, 0, 0, Sb, kS, 0, 0, kD, nullptr, lr0, 0);
        k_gemm<3><<<dim3(16, 4, 1), 256, 0, stream>>>(
            Sb, kS, 0, 0, VTbh, kS, 0, 0, AObh, kD, 0, 0, kS, nullptr, lr0, 0);
        float* outb = out + (size_t)b * kS * kD;
        if (h == 0)
          k_gemm<1><<<dim3(16, 4), 256, 0, stream>>>(
              AObh, kD, 0, 0, owT, kND, 0, 0, outb, kD, 0, 0, kD, o_b, nullptr,
              0);
        else
          k_gemm<4><<<dim3(16, 4), 256, 0, stream>>>(
              AObh, kD, 0, 0, owT + (size_t)h * kD, kND, 0, 0, outb, kD, 0, 0,
              kD, nullptr, nullptr, 0);
      }
  }
}